// Round 5
// baseline (96.862 us; speedup 1.0000x reference)
//
#include <hip/hip_runtime.h>

// YOLO loss forward, MI355X — round 5.
// R4 post-mortem: right structure (coalesced global_load_lds staging, ideal
// 86MB FETCH) but only 2 blocks/CU (8 waves) to hide the vmcnt(0) drain, plus
// a serial 1-block reduce kernel on the tail. This round: 128-cell tiles
// (28.16KB LDS -> 5 blocks/CU, 10 waves, 6272 streaming blocks) and a fused
// atomicAdd reduction (hipMemsetAsync zeroes d_out in-graph each replay).

#define TPB 128
#define NBLK 6272                     // 802816 / 128, exact

#define GP(x) ((const __attribute__((address_space(1))) void*)(x))
#define LP(x) ((__attribute__((address_space(3))) void*)(x))

__device__ __forceinline__ float iou_f(float a0, float a1, float a2, float a3,
                                       float b0, float b1, float b2, float b3) {
    float ax1 = a0 - a2 * 0.5f, ax2 = a0 + a2 * 0.5f;
    float ay1 = a1 - a3 * 0.5f, ay2 = a1 + a3 * 0.5f;
    float bx1 = b0 - b2 * 0.5f, bx2 = b0 + b2 * 0.5f;
    float by1 = b1 - b3 * 0.5f, by2 = b1 + b3 * 0.5f;
    float iw = fmaxf(fminf(ax2, bx2) - fmaxf(ax1, bx1), 0.0f);
    float ih = fmaxf(fminf(ay2, by2) - fmaxf(ay1, by1), 0.0f);
    float inter = iw * ih;
    float aa = fabsf(a2 * a3);
    float ab = fabsf(b2 * b3);
    return inter / (aa + ab - inter + 1e-6f);
}

__global__ __launch_bounds__(TPB) void yolo_cell(
    const float* __restrict__ pred, const float* __restrict__ targ,
    float* __restrict__ out) {
    __shared__ __align__(16) float sp[TPB * 30];   // 15360 B, [128][30] packed
    __shared__ __align__(16) float st[TPB * 25];   // 12800 B, [128][25] packed
    __shared__ float swr[2];

    const int tid = threadIdx.x;
    const int w = tid >> 6;            // 0..1
    const int l = tid & 63;

    // ---- stage this block's 128 cells, fully coalesced, identity LDS layout
    const char* ps = (const char*)pred + (size_t)blockIdx.x * (TPB * 120); // 15360 B
    const char* ts = (const char*)targ + (size_t)blockIdx.x * (TPB * 100); // 12800 B

#pragma unroll
    for (int j = 0; j < 7; ++j)        // 7 * 2048 = 14336 B of pred (both waves, w16)
        __builtin_amdgcn_global_load_lds(GP(ps + j * 2048 + w * 1024 + l * 16),
                                         LP((char*)sp + j * 2048 + w * 1024), 16, 0, 0);
    if (w == 0)                        // last 1024 B of pred
        __builtin_amdgcn_global_load_lds(GP(ps + 14336 + l * 16),
                                         LP((char*)sp + 14336), 16, 0, 0);
#pragma unroll
    for (int j = 0; j < 6; ++j)        // 6 * 2048 = 12288 B of targ (both waves, w16)
        __builtin_amdgcn_global_load_lds(GP(ts + j * 2048 + w * 1024 + l * 16),
                                         LP((char*)st + j * 2048 + w * 1024), 16, 0, 0);
    // last 512 B of targ (both waves, w4)
    __builtin_amdgcn_global_load_lds(GP(ts + 12288 + w * 256 + l * 4),
                                     LP((char*)st + 12288 + w * 256), 4, 0, 0);

    asm volatile("s_waitcnt vmcnt(0)" ::: "memory");
    __syncthreads();

    // ---- per-cell loss from LDS
    const float2* p2 = (const float2*)(sp + tid * 30);  // 8B-aligned (30 even)
    float pv[30];
#pragma unroll
    for (int j = 0; j < 15; ++j) {
        float2 v = p2[j];
        pv[2 * j]     = v.x;
        pv[2 * j + 1] = v.y;
    }
    const float* T = st + tid * 25;
    float tv[25];
#pragma unroll
    for (int j = 0; j < 25; ++j) tv[j] = T[j];

    float cls = 0.0f;
#pragma unroll
    for (int j = 0; j < 20; ++j) {
        float d = pv[j] - tv[j];
        cls += d * d;
    }

    float t0 = tv[20], t1 = tv[21], t2 = tv[22], t3 = tv[23], t4v = tv[24];
    bool obj = (t0 == 1.0f);

    float i1 = iou_f(pv[20], pv[21], pv[22], pv[23], t0, t1, t2, t3);
    float i2 = iou_f(pv[25], pv[26], pv[27], pv[28], t0, t1, t2, t3);
    bool use1 = i1 > i2;

    float r0 = use1 ? pv[20] : pv[25];
    float r1 = use1 ? pv[21] : pv[26];
    float r2 = use1 ? pv[22] : pv[27];
    float r3 = use1 ? pv[23] : pv[28];
    float r4 = use1 ? pv[24] : pv[29];
    float oc = use1 ? pv[29] : pv[24];

    float dx = r0 - t0;
    float dy = r1 - t1;
    float dw = sqrtf(fmaxf(r2, 1e-6f)) - sqrtf(fmaxf(t2, 1e-6f));
    float dh = sqrtf(fmaxf(r3, 1e-6f)) - sqrtf(fmaxf(t3, 1e-6f));
    float coord = 5.0f * (dx * dx + dy * dy + dw * dw + dh * dh);

    float dconf = r4 - t4v;
    float obj_conf = dconf * dconf;

    float noobj_in = 0.5f * oc * oc;
    float noobj_out = 0.5f * (pv[24] * pv[24] + pv[29] * pv[29]);

    float lsum = obj ? (coord + obj_conf + cls + noobj_in) : noobj_out;

    // ---- block reduction (fixed order per block) + one atomic per block
#pragma unroll
    for (int off = 32; off > 0; off >>= 1) lsum += __shfl_down(lsum, off, 64);
    if (l == 0) swr[w] = lsum;
    __syncthreads();
    if (tid == 0) atomicAdd(out, (swr[0] + swr[1]) * (1.0f / 16384.0f));
}

extern "C" void kernel_launch(void* const* d_in, const int* in_sizes, int n_in,
                              void* d_out, int out_size, void* d_ws, size_t ws_size,
                              hipStream_t stream) {
    const float* pred = (const float*)d_in[0];
    const float* targ = (const float*)d_in[1];
    float* out = (float*)d_out;

    hipMemsetAsync(out, 0, sizeof(float), stream);   // re-zero each graph replay
    yolo_cell<<<NBLK, TPB, 0, stream>>>(pred, targ, out);
}

// Round 6
// 37.970 us; speedup vs baseline: 2.5510x; 2.5510x over previous
//
#include <hip/hip_runtime.h>

// YOLO loss forward, MI355X — round 6.
// R5 post-mortem: fused single-address atomicAdd (6272 device-scope f32 RMWs
// to one line, serialized at the cross-XCD coherence point) added ~+35us and
// delayed block retirement. This round isolates that variable: keep R5's
// fine-grained streaming (TPB=128, 28.7KB LDS -> 5 blocks/CU, 10 waves/CU,
// 6272 blocks), restore the deterministic two-kernel reduction (no atomics).

#define TPB 128
#define NBLK 6272                     // 802816 / 128, exact
constexpr int NPART = NBLK;

#define GP(x) ((const __attribute__((address_space(1))) void*)(x))
#define LP(x) ((__attribute__((address_space(3))) void*)(x))

__device__ __forceinline__ float iou_f(float a0, float a1, float a2, float a3,
                                       float b0, float b1, float b2, float b3) {
    float ax1 = a0 - a2 * 0.5f, ax2 = a0 + a2 * 0.5f;
    float ay1 = a1 - a3 * 0.5f, ay2 = a1 + a3 * 0.5f;
    float bx1 = b0 - b2 * 0.5f, bx2 = b0 + b2 * 0.5f;
    float by1 = b1 - b3 * 0.5f, by2 = b1 + b3 * 0.5f;
    float iw = fmaxf(fminf(ax2, bx2) - fmaxf(ax1, bx1), 0.0f);
    float ih = fmaxf(fminf(ay2, by2) - fmaxf(ay1, by1), 0.0f);
    float inter = iw * ih;
    float aa = fabsf(a2 * a3);
    float ab = fabsf(b2 * b3);
    return inter / (aa + ab - inter + 1e-6f);
}

__global__ __launch_bounds__(TPB) void yolo_cell(
    const float* __restrict__ pred, const float* __restrict__ targ,
    float* __restrict__ part) {
    __shared__ __align__(16) float sp[TPB * 30];   // 15360 B, [128][30] packed
    __shared__ __align__(16) float st[TPB * 25];   // 12800 B, [128][25] packed
    __shared__ float swr[2];

    const int tid = threadIdx.x;
    const int w = tid >> 6;            // 0..1
    const int l = tid & 63;

    // ---- stage this block's 128 cells, fully coalesced, identity LDS layout
    const char* ps = (const char*)pred + (size_t)blockIdx.x * (TPB * 120); // 15360 B
    const char* ts = (const char*)targ + (size_t)blockIdx.x * (TPB * 100); // 12800 B

#pragma unroll
    for (int j = 0; j < 7; ++j)        // 7 * 2048 = 14336 B of pred (both waves, w16)
        __builtin_amdgcn_global_load_lds(GP(ps + j * 2048 + w * 1024 + l * 16),
                                         LP((char*)sp + j * 2048 + w * 1024), 16, 0, 0);
    if (w == 0)                        // last 1024 B of pred
        __builtin_amdgcn_global_load_lds(GP(ps + 14336 + l * 16),
                                         LP((char*)sp + 14336), 16, 0, 0);
#pragma unroll
    for (int j = 0; j < 6; ++j)        // 6 * 2048 = 12288 B of targ (both waves, w16)
        __builtin_amdgcn_global_load_lds(GP(ts + j * 2048 + w * 1024 + l * 16),
                                         LP((char*)st + j * 2048 + w * 1024), 16, 0, 0);
    // last 512 B of targ (both waves, w4)
    __builtin_amdgcn_global_load_lds(GP(ts + 12288 + w * 256 + l * 4),
                                     LP((char*)st + 12288 + w * 256), 4, 0, 0);

    asm volatile("s_waitcnt vmcnt(0)" ::: "memory");
    __syncthreads();

    // ---- per-cell loss from LDS
    const float2* p2 = (const float2*)(sp + tid * 30);  // 8B-aligned (30 even)
    float pv[30];
#pragma unroll
    for (int j = 0; j < 15; ++j) {
        float2 v = p2[j];
        pv[2 * j]     = v.x;
        pv[2 * j + 1] = v.y;
    }
    const float* T = st + tid * 25;
    float tv[25];
#pragma unroll
    for (int j = 0; j < 25; ++j) tv[j] = T[j];

    float cls = 0.0f;
#pragma unroll
    for (int j = 0; j < 20; ++j) {
        float d = pv[j] - tv[j];
        cls += d * d;
    }

    float t0 = tv[20], t1 = tv[21], t2 = tv[22], t3 = tv[23], t4v = tv[24];
    bool obj = (t0 == 1.0f);

    float i1 = iou_f(pv[20], pv[21], pv[22], pv[23], t0, t1, t2, t3);
    float i2 = iou_f(pv[25], pv[26], pv[27], pv[28], t0, t1, t2, t3);
    bool use1 = i1 > i2;

    float r0 = use1 ? pv[20] : pv[25];
    float r1 = use1 ? pv[21] : pv[26];
    float r2 = use1 ? pv[22] : pv[27];
    float r3 = use1 ? pv[23] : pv[28];
    float r4 = use1 ? pv[24] : pv[29];
    float oc = use1 ? pv[29] : pv[24];

    float dx = r0 - t0;
    float dy = r1 - t1;
    float dw = sqrtf(fmaxf(r2, 1e-6f)) - sqrtf(fmaxf(t2, 1e-6f));
    float dh = sqrtf(fmaxf(r3, 1e-6f)) - sqrtf(fmaxf(t3, 1e-6f));
    float coord = 5.0f * (dx * dx + dy * dy + dw * dw + dh * dh);

    float dconf = r4 - t4v;
    float obj_conf = dconf * dconf;

    float noobj_in = 0.5f * oc * oc;
    float noobj_out = 0.5f * (pv[24] * pv[24] + pv[29] * pv[29]);

    float lsum = obj ? (coord + obj_conf + cls + noobj_in) : noobj_out;

    // ---- block reduction (fixed order -> deterministic), no atomics
#pragma unroll
    for (int off = 32; off > 0; off >>= 1) lsum += __shfl_down(lsum, off, 64);
    if (l == 0) swr[w] = lsum;
    __syncthreads();
    if (tid == 0) part[blockIdx.x] = swr[0] + swr[1];
}

__global__ __launch_bounds__(256) void yolo_reduce(const float* __restrict__ part,
                                                   float* __restrict__ out) {
    __shared__ float swr[4];
    const int tid = threadIdx.x;
    float s = 0.0f;
    for (int i = tid; i < NPART; i += 256) s += part[i];
#pragma unroll
    for (int off = 32; off > 0; off >>= 1) s += __shfl_down(s, off, 64);
    if ((tid & 63) == 0) swr[tid >> 6] = s;
    __syncthreads();
    if (tid == 0) out[0] = (swr[0] + swr[1] + swr[2] + swr[3]) * (1.0f / 16384.0f);
}

extern "C" void kernel_launch(void* const* d_in, const int* in_sizes, int n_in,
                              void* d_out, int out_size, void* d_ws, size_t ws_size,
                              hipStream_t stream) {
    const float* pred = (const float*)d_in[0];
    const float* targ = (const float*)d_in[1];
    float* part = (float*)d_ws;   // NPART floats = 25 KB
    float* out = (float*)d_out;

    yolo_cell<<<NBLK, TPB, 0, stream>>>(pred, targ, part);
    yolo_reduce<<<1, 256, 0, stream>>>(part, out);
}

// Round 7
// 35.950 us; speedup vs baseline: 2.6944x; 1.0562x over previous
//
#include <hip/hip_runtime.h>

// YOLO loss forward, MI355X — round 7.
// R6 post-mortem: TPB=128 and TPB=256 variants run identical profiled dur
// (61us) — structure plateaued at ~5.1 TB/s, latency-bound (20% occupancy,
// full vmcnt(0) drain per block, 2-5 blocks/CU). This round: TPB=64 (one
// wave per block), 64-cell tiles, 14.08KB LDS -> 11 blocks/CU (~150KB staged
// in flight per CU), NO __syncthreads / NO cross-wave reduce (wave-synchronous
// block), 12544 streaming blocks. Reduce kernel widened to 1024 threads.

#define TPB 64
#define NBLK 12544                    // 802816 / 64, exact
constexpr int NPART = NBLK;

#define GP(x) ((const __attribute__((address_space(1))) void*)(x))
#define LP(x) ((__attribute__((address_space(3))) void*)(x))

__device__ __forceinline__ float iou_f(float a0, float a1, float a2, float a3,
                                       float b0, float b1, float b2, float b3) {
    float ax1 = a0 - a2 * 0.5f, ax2 = a0 + a2 * 0.5f;
    float ay1 = a1 - a3 * 0.5f, ay2 = a1 + a3 * 0.5f;
    float bx1 = b0 - b2 * 0.5f, bx2 = b0 + b2 * 0.5f;
    float by1 = b1 - b3 * 0.5f, by2 = b1 + b3 * 0.5f;
    float iw = fmaxf(fminf(ax2, bx2) - fmaxf(ax1, bx1), 0.0f);
    float ih = fmaxf(fminf(ay2, by2) - fmaxf(ay1, by1), 0.0f);
    float inter = iw * ih;
    float aa = fabsf(a2 * a3);
    float ab = fabsf(b2 * b3);
    return inter / (aa + ab - inter + 1e-6f);
}

__global__ __launch_bounds__(TPB) void yolo_cell(
    const float* __restrict__ pred, const float* __restrict__ targ,
    float* __restrict__ part) {
    __shared__ __align__(16) float sp[TPB * 30];   // 7680 B, [64][30] packed
    __shared__ __align__(16) float st[TPB * 25];   // 6400 B, [64][25] packed

    const int l = threadIdx.x;         // single wave: tid == lane

    // ---- stage this block's 64 cells, fully coalesced, identity LDS layout
    const char* ps = (const char*)pred + (size_t)blockIdx.x * (TPB * 120); // 7680 B
    const char* ts = (const char*)targ + (size_t)blockIdx.x * (TPB * 100); // 6400 B

#pragma unroll
    for (int j = 0; j < 7; ++j)        // 7 * 1024 = 7168 B of pred (w16)
        __builtin_amdgcn_global_load_lds(GP(ps + j * 1024 + l * 16),
                                         LP((char*)sp + j * 1024), 16, 0, 0);
#pragma unroll
    for (int j = 0; j < 2; ++j)        // last 512 B of pred (w4)
        __builtin_amdgcn_global_load_lds(GP(ps + 7168 + j * 256 + l * 4),
                                         LP((char*)sp + 7168 + j * 256), 4, 0, 0);
#pragma unroll
    for (int j = 0; j < 6; ++j)        // 6 * 1024 = 6144 B of targ (w16)
        __builtin_amdgcn_global_load_lds(GP(ts + j * 1024 + l * 16),
                                         LP((char*)st + j * 1024), 16, 0, 0);
    __builtin_amdgcn_global_load_lds(GP(ts + 6144 + l * 4),
                                     LP((char*)st + 6144), 4, 0, 0); // last 256 B (w4)

    asm volatile("s_waitcnt vmcnt(0)" ::: "memory");
    // single-wave block: no __syncthreads needed

    // ---- per-cell loss from LDS
    const float2* p2 = (const float2*)(sp + l * 30);  // 8B-aligned (30 even)
    float pv[30];
#pragma unroll
    for (int j = 0; j < 15; ++j) {
        float2 v = p2[j];
        pv[2 * j]     = v.x;
        pv[2 * j + 1] = v.y;
    }
    const float* T = st + l * 25;
    float tv[25];
#pragma unroll
    for (int j = 0; j < 25; ++j) tv[j] = T[j];

    float cls = 0.0f;
#pragma unroll
    for (int j = 0; j < 20; ++j) {
        float d = pv[j] - tv[j];
        cls += d * d;
    }

    float t0 = tv[20], t1 = tv[21], t2 = tv[22], t3 = tv[23], t4v = tv[24];
    bool obj = (t0 == 1.0f);

    float i1 = iou_f(pv[20], pv[21], pv[22], pv[23], t0, t1, t2, t3);
    float i2 = iou_f(pv[25], pv[26], pv[27], pv[28], t0, t1, t2, t3);
    bool use1 = i1 > i2;

    float r0 = use1 ? pv[20] : pv[25];
    float r1 = use1 ? pv[21] : pv[26];
    float r2 = use1 ? pv[22] : pv[27];
    float r3 = use1 ? pv[23] : pv[28];
    float r4 = use1 ? pv[24] : pv[29];
    float oc = use1 ? pv[29] : pv[24];

    float dx = r0 - t0;
    float dy = r1 - t1;
    float dw = sqrtf(fmaxf(r2, 1e-6f)) - sqrtf(fmaxf(t2, 1e-6f));
    float dh = sqrtf(fmaxf(r3, 1e-6f)) - sqrtf(fmaxf(t3, 1e-6f));
    float coord = 5.0f * (dx * dx + dy * dy + dw * dw + dh * dh);

    float dconf = r4 - t4v;
    float obj_conf = dconf * dconf;

    float noobj_in = 0.5f * oc * oc;
    float noobj_out = 0.5f * (pv[24] * pv[24] + pv[29] * pv[29]);

    float lsum = obj ? (coord + obj_conf + cls + noobj_in) : noobj_out;

    // ---- wave reduction (fixed order -> deterministic), no barriers
#pragma unroll
    for (int off = 32; off > 0; off >>= 1) lsum += __shfl_down(lsum, off, 64);
    if (l == 0) part[blockIdx.x] = lsum;
}

__global__ __launch_bounds__(1024) void yolo_reduce(const float* __restrict__ part,
                                                    float* __restrict__ out) {
    __shared__ float swr[16];
    const int tid = threadIdx.x;
    float s = 0.0f;
    for (int i = tid; i < NPART; i += 1024) s += part[i];
#pragma unroll
    for (int off = 32; off > 0; off >>= 1) s += __shfl_down(s, off, 64);
    if ((tid & 63) == 0) swr[tid >> 6] = s;
    __syncthreads();
    if (tid == 0) {
        float t = 0.0f;
#pragma unroll
        for (int i = 0; i < 16; ++i) t += swr[i];
        out[0] = t * (1.0f / 16384.0f);
    }
}

extern "C" void kernel_launch(void* const* d_in, const int* in_sizes, int n_in,
                              void* d_out, int out_size, void* d_ws, size_t ws_size,
                              hipStream_t stream) {
    const float* pred = (const float*)d_in[0];
    const float* targ = (const float*)d_in[1];
    float* part = (float*)d_ws;   // NPART floats = 50 KB
    float* out = (float*)d_out;

    yolo_cell<<<NBLK, TPB, 0, stream>>>(pred, targ, part);
    yolo_reduce<<<1, 1024, 0, stream>>>(part, out);
}